// Round 6
// baseline (602.560 us; speedup 1.0000x reference)
//
#include <hip/hip_runtime.h>
#include <hip/hip_bf16.h>

// B=64 batch, T=512 enc timesteps, E=1024 enc hidden, D=1024 dec hidden
// ALL inputs/outputs are FLOAT32 (per reference setup_inputs).
#define BB 64
#define TT 512
#define EE 1024
#define DD 1024
// Fused e-proj GEMM: M = T*B = 32768, N = 2E = 2048, K = E = 1024 (bf16 MFMA)

typedef __attribute__((ext_vector_type(8))) short s16x8;   // 8 bf16 MFMA A/B frag
typedef __attribute__((ext_vector_type(4))) float f32x4;   // MFMA C/D frag

__device__ __forceinline__ float bf2f(unsigned short u) {
    unsigned int x = ((unsigned int)u) << 16;
    return __builtin_bit_cast(float, x);
}
__device__ __forceinline__ unsigned short f2bf(float f) {   // RNE, finite inputs
    unsigned int u = __builtin_bit_cast(unsigned int, f);
    u += 0x7FFF + ((u >> 16) & 1);
    return (unsigned short)(u >> 16);
}
__device__ __forceinline__ float tanh_fast(float x) {
    x = fminf(fmaxf(x, -15.f), 15.f);
    float e = __expf(2.f * x);
    return (e - 1.f) / (e + 1.f);
}

// Fragment-order slot for chunk (row 0..127, g 0..7) in a 128x64 tile:
//   slot = (row>>4)*128 + (g>>2)*64 + (g&3)*16 + (row&15)
// Fragment (m16, kk) = slots m16*128 + kk*64 + [lane 0..63]  -> lane holds
// A[row=m16*16+(lane&15)][k=kk*32+(lane>>4)*8 .. +8]  (16x16x32 A/B layout).
__device__ __forceinline__ int tile_slot(int row, int g) {
    return (row >> 4) * 128 + (g >> 2) * 64 + (g & 3) * 16 + (row & 15);
}

// ---------------------------------------------------------------------------
// enc f32 [32768,1024] -> encS bf16 tiled (tm 0..255, tk 0..15), fragment
// order, 16 KB/tile. grid (256,16), block 256.
// ---------------------------------------------------------------------------
__global__ __launch_bounds__(256) void conv_encS_kernel(
    const float* __restrict__ enc, unsigned short* __restrict__ encS)
{
    const int tm  = blockIdx.x;
    const int tk  = blockIdx.y;
    const int tid = threadIdx.x;
    unsigned short* dst = encS + ((size_t)tm * 16 + tk) * 8192;

#pragma unroll
    for (int it = 0; it < 4; ++it) {
        int cidx = it * 256 + tid;       // chunk id 0..1023
        int row  = cidx >> 3;            // 0..127
        int g    = cidx & 7;             // 0..7
        const float* src = enc + (size_t)(tm * 128 + row) * 1024 + tk * 64 + g * 8;
        float4 v0 = ((const float4*)src)[0];
        float4 v1 = ((const float4*)src)[1];
        short c[8];
        c[0] = (short)f2bf(v0.x); c[1] = (short)f2bf(v0.y);
        c[2] = (short)f2bf(v0.z); c[3] = (short)f2bf(v0.w);
        c[4] = (short)f2bf(v1.x); c[5] = (short)f2bf(v1.y);
        c[6] = (short)f2bf(v1.z); c[7] = (short)f2bf(v1.w);
        *(s16x8*)&dst[tile_slot(row, g) * 8] = *(s16x8*)c;
    }
}

// ---------------------------------------------------------------------------
// Wa[:,1024:2048] f32 -> WaS bf16 tiled (tn 0..15, tk 0..15). grid (16,16).
// ---------------------------------------------------------------------------
__global__ __launch_bounds__(256) void conv_waS_kernel(
    const float* __restrict__ Wa, unsigned short* __restrict__ WaS)
{
    const int tn  = blockIdx.x;
    const int tk  = blockIdx.y;
    const int tid = threadIdx.x;
    unsigned short* dst = WaS + ((size_t)tn * 16 + tk) * 8192;

#pragma unroll
    for (int it = 0; it < 4; ++it) {
        int cidx = it * 256 + tid;
        int row  = cidx >> 3;            // f within tile
        int g    = cidx & 7;
        const float* src = Wa + (size_t)(tn * 128 + row) * 2048 + 1024 + tk * 64 + g * 8;
        float4 v0 = ((const float4*)src)[0];
        float4 v1 = ((const float4*)src)[1];
        short c[8];
        c[0] = (short)f2bf(v0.x); c[1] = (short)f2bf(v0.y);
        c[2] = (short)f2bf(v0.z); c[3] = (short)f2bf(v0.w);
        c[4] = (short)f2bf(v1.x); c[5] = (short)f2bf(v1.y);
        c[6] = (short)f2bf(v1.z); c[7] = (short)f2bf(v1.w);
        *(s16x8*)&dst[tile_slot(row, g) * 8] = *(s16x8*)c;
    }
}

// ---------------------------------------------------------------------------
// hproj[f][b] = hidden[b,:1024] . Wa[f,:1024] + ba[f]   (f-major, f32)
// ---------------------------------------------------------------------------
__global__ __launch_bounds__(256) void hproj_kernel(
    const float* __restrict__ hidden,   // [64,1024]
    const float* __restrict__ Wa,       // [2048,2048]
    const float* __restrict__ ba,       // [2048]
    float* __restrict__ hp)             // [2048*64]
{
    __shared__ float sW[8 * 1024];      // 32 KB
    const int tid  = threadIdx.x;
    const int lane = tid & 63;
    const int wave = tid >> 6;
    const int f0   = blockIdx.x * 8;

#pragma unroll
    for (int i = 0; i < 8; ++i) {
        int idx = i * 256 + tid;
        int fi  = idx >> 8;
        int c4  = idx & 255;
        ((float4*)sW)[idx] = *(const float4*)(Wa + (size_t)(f0 + fi) * 2048 + c4 * 4);
    }
    __syncthreads();

    for (int bi = 0; bi < 16; ++bi) {
        int b = wave * 16 + bi;
        float h[16];
#pragma unroll
        for (int j = 0; j < 16; ++j) h[j] = hidden[b * 1024 + lane + 64 * j];
#pragma unroll
        for (int fi = 0; fi < 8; ++fi) {
            float s = 0.f;
#pragma unroll
            for (int j = 0; j < 16; ++j) s += h[j] * sW[fi * 1024 + lane + 64 * j];
#pragma unroll
            for (int m = 32; m; m >>= 1) s += __shfl_xor(s, m);
            if (lane == 0) hp[(f0 + fi) * 64 + b] = s + ba[f0 + fi];
        }
    }
}

// ---------------------------------------------------------------------------
// Fused e_proj GEMM + tanh + w2-dot -> per-bn partial scores.
// Direct global->VGPR fragments (pre-swizzled tiles), register dbuf,
// barrier-free K-loop. Round 6 changes vs R5 (latency attack):
//  * grid (8 bn, 256 bm), bn fastest -> XCD = dispatch_id % 8 = bn:
//    each WaS column tile (2 MB) pins in its XCD's 4 MB L2; all 8 XCDs
//    run the same bm concurrently -> each encS tile is HBM-fetched once,
//    then L3-served. enc streams through L3 ONCE (was 8x).
//  * K-loop stagger: wave wm starts its (order-independent) K-sum at
//    ktile wm*8 -> block waves desync, covering each other's load stalls.
// Wave tile 64x128 (4 mi x 8 ni), block = 4 waves = 128x256.
// ---------------------------------------------------------------------------
__global__ __launch_bounds__(256, 2) void gemm_scores(
    const unsigned short* __restrict__ encS,  // tiled bf16 (ws)
    const unsigned short* __restrict__ WaS,   // tiled bf16 (ws)
    const float* __restrict__ hp,             // [2048*64] f32, f-major
    const float* __restrict__ w2,             // [2048] f32
    float* __restrict__ scoresP)              // [8][64][512] partials
{
    __shared__ float rowAcc[128];

    const int tid  = threadIdx.x;
    const int bn   = blockIdx.x;   // 0..7   col tile (256 f)  [fastest -> XCD pin]
    const int bm   = blockIdx.y;   // 0..255 row tile (128 rows)
    const int lane = tid & 63;
    const int wave = tid >> 6;
    const int wm   = wave >> 1;    // 0..1: rows wm*64
    const int wn   = wave & 1;     // 0..1: f-tile tn = bn*2+wn
    const int c    = lane & 15;
    const int quad = lane >> 4;
    const int off  = wm * 16;      // K-stagger (half-K per wm) in h units

    if (tid < 128) rowAcc[tid] = 0.f;

    f32x4 acc[4][8];
#pragma unroll
    for (int mi = 0; mi < 4; ++mi)
#pragma unroll
        for (int ni = 0; ni < 8; ++ni)
#pragma unroll
            for (int r = 0; r < 4; ++r) acc[mi][ni][r] = 0.f;

    // A frag (mi, h): encS[(bm*16 + h/2)*8192 + wm*4096 + (h&1)*512 + mi*1024 + lane*8]
    // B frag (ni, h): WaS [((bn*2+wn)*16 + h/2)*8192 + (h&1)*512 + ni*1024 + lane*8]
    const unsigned short* aBase = encS + (size_t)bm * 16 * 8192 + wm * 4096 + lane * 8;
    const unsigned short* bBase = WaS + ((size_t)(bn * 2 + wn) * 16) * 8192 + lane * 8;

    s16x8 aF[2][4], bF[2][8];

    {
        const int h0 = off;     // first h in this wave's sequence
        const unsigned short* pa = aBase + (h0 >> 1) * 8192 + (h0 & 1) * 512;
        const unsigned short* pb = bBase + (h0 >> 1) * 8192 + (h0 & 1) * 512;
#pragma unroll
        for (int mi = 0; mi < 4; ++mi) aF[0][mi] = *(const s16x8*)(pa + mi * 1024);
#pragma unroll
        for (int ni = 0; ni < 8; ++ni) bF[0][ni] = *(const s16x8*)(pb + ni * 1024);
    }

#pragma unroll
    for (int i = 0; i < 32; ++i) {
        const int cur = i & 1;
        const int nxt = cur ^ 1;
        if (i < 31) {
            const int h1 = ((i + 1) + off) & 31;   // next h in wave's sequence
            const unsigned short* pa = aBase + (h1 >> 1) * 8192 + (h1 & 1) * 512;
            const unsigned short* pb = bBase + (h1 >> 1) * 8192 + (h1 & 1) * 512;
#pragma unroll
            for (int mi = 0; mi < 4; ++mi)
                aF[nxt][mi] = *(const s16x8*)(pa + mi * 1024);
#pragma unroll
            for (int ni = 0; ni < 8; ++ni)
                bF[nxt][ni] = *(const s16x8*)(pb + ni * 1024);
        }
#pragma unroll
        for (int mi = 0; mi < 4; ++mi)
#pragma unroll
            for (int ni = 0; ni < 8; ++ni)
                acc[mi][ni] = __builtin_amdgcn_mfma_f32_16x16x32_bf16(
                    aF[cur][mi], bF[cur][ni], acc[mi][ni], 0, 0, 0);
    }

    __syncthreads();   // rowAcc init visible

    // Epilogue: rowAcc[row] += sum_f tanh(C + hp) * w2 over this wave's 128 f.
    float w2v[8];
#pragma unroll
    for (int ni = 0; ni < 8; ++ni)
        w2v[ni] = w2[bn * 256 + wn * 128 + ni * 16 + c];

#pragma unroll
    for (int mi = 0; mi < 4; ++mi) {
        int lrow0 = wm * 64 + mi * 16 + quad * 4;       // quad*4-aligned
        int b0    = (bm * 128 + lrow0) & 63;            // float4-aligned
        f32x4 hp4[8];
#pragma unroll
        for (int ni = 0; ni < 8; ++ni)
            hp4[ni] = *(const f32x4*)&hp[(bn * 256 + wn * 128 + ni * 16 + c) * 64 + b0];
#pragma unroll
        for (int r = 0; r < 4; ++r) {
            float s = 0.f;
#pragma unroll
            for (int ni = 0; ni < 8; ++ni)
                s += tanh_fast(acc[mi][ni][r] + hp4[ni][r]) * w2v[ni];
            s += __shfl_xor(s, 1);
            s += __shfl_xor(s, 2);
            s += __shfl_xor(s, 4);
            s += __shfl_xor(s, 8);
            if (c == 0) atomicAdd(&rowAcc[lrow0 + r], s);
        }
    }
    __syncthreads();
    if (tid < 128) {
        int grow = bm * 128 + tid;
        int b = grow & 63;
        int t = grow >> 6;
        scoresP[((size_t)bn * 64 + b) * 512 + t] = rowAcc[tid];
    }
}

// ---------------------------------------------------------------------------
// Softmax over T: sum 8 bn-partials, softmax, write weights [64][512].
// ---------------------------------------------------------------------------
__global__ __launch_bounds__(256) void softmax_kernel(
    const float* __restrict__ scoresP, float* __restrict__ weights)
{
    __shared__ float wmax[4];
    __shared__ float wsum[4];
    const int b   = blockIdx.x;
    const int tid = threadIdx.x;

    float v0 = 0.f, v1 = 0.f;
#pragma unroll
    for (int p = 0; p < 8; ++p) {
        const float* row = scoresP + ((size_t)p * 64 + b) * 512;
        v0 += row[tid];
        v1 += row[tid + 256];
    }
    float m = fmaxf(v0, v1);
#pragma unroll
    for (int s = 32; s; s >>= 1) m = fmaxf(m, __shfl_xor(m, s));
    if ((tid & 63) == 0) wmax[tid >> 6] = m;
    __syncthreads();
    m = fmaxf(fmaxf(wmax[0], wmax[1]), fmaxf(wmax[2], wmax[3]));

    float e0 = __expf(v0 - m), e1 = __expf(v1 - m);
    float s = e0 + e1;
#pragma unroll
    for (int t = 32; t; t >>= 1) s += __shfl_xor(s, t);
    if ((tid & 63) == 0) wsum[tid >> 6] = s;
    __syncthreads();
    float inv = 1.f / (wsum[0] + wsum[1] + wsum[2] + wsum[3]);
    float* row = weights + (size_t)b * 512;
    row[tid]       = e0 * inv;
    row[tid + 256] = e1 * inv;
}

// ---------------------------------------------------------------------------
// applied partials from original f32 enc (coalesced):
// part[tc][b][e] = sum_{t in chunk tc} w[b,t]*enc[t,b,e]
// grid = (16 tc, 64 b), block = 256: 128 e-owners x 2 t-halves
// ---------------------------------------------------------------------------
__global__ __launch_bounds__(256) void applied_part_kernel(
    const float* __restrict__ enc,            // [T,B,E] f32
    const float* __restrict__ w,              // [64,512] weights
    float* __restrict__ part)                 // [16][64][1024]
{
    __shared__ float red[128 * 8];
    const int tc  = blockIdx.x;
    const int b   = blockIdx.y;
    const int tid = threadIdx.x;
    const int eo  = tid & 127;
    const int th  = tid >> 7;
    const int e0  = eo * 8;

    float a[8];
#pragma unroll
    for (int j = 0; j < 8; ++j) a[j] = 0.f;

    for (int it = 0; it < 16; ++it) {
        int t = tc * 32 + th * 16 + it;
        float wt = w[b * TT + t];
        const float* src = enc + ((size_t)(t * BB + b)) * EE + e0;
        float4 v0 = ((const float4*)src)[0];
        float4 v1 = ((const float4*)src)[1];
        a[0] += wt * v0.x; a[1] += wt * v0.y; a[2] += wt * v0.z; a[3] += wt * v0.w;
        a[4] += wt * v1.x; a[5] += wt * v1.y; a[6] += wt * v1.z; a[7] += wt * v1.w;
    }
    if (th == 1) {
#pragma unroll
        for (int j = 0; j < 8; ++j) red[eo * 8 + j] = a[j];
    }
    __syncthreads();
    if (th == 0) {
        float* dst = part + ((size_t)tc * 64 + b) * 1024 + e0;
#pragma unroll
        for (int j = 0; j < 8; ++j) dst[j] = a[j] + red[eo * 8 + j];
    }
}

// reduce 16 partials -> applied (output 1, f32) at out+65536
__global__ __launch_bounds__(256) void applied_reduce_kernel(
    const float* __restrict__ part, float* __restrict__ out_applied)
{
    int idx = blockIdx.x * 256 + threadIdx.x;
    float s = 0.f;
#pragma unroll
    for (int tc = 0; tc < 16; ++tc) s += part[tc * 65536 + idx];
    out_applied[idx] = s;
}

// ---------------------------------------------------------------------------
// out[b,d] = tanh(dec[b].Wc[d,:1024] + applied[b].Wc[d,1024:] + bc[d])
// ---------------------------------------------------------------------------
__global__ __launch_bounds__(256) void combine_kernel(
    const float* __restrict__ dec,       // [64,1024]
    const float* applied,                // [64,1024] (= out+65536)
    const float* __restrict__ Wc,        // [1024,2048]
    const float* __restrict__ bc,        // [1024]
    float* out0)                         // first 65536 of d_out
{
    const int g    = blockIdx.x * 4 + (threadIdx.x >> 6);
    const int lane = threadIdx.x & 63;
    const int d    = g >> 6;
    const int b    = g & 63;

    const float4* wc4 = (const float4*)Wc + (size_t)d * 512;
    const float4* de4 = (const float4*)dec + (size_t)b * 256;
    const float4* ap4 = (const float4*)applied + (size_t)b * 256;

    float s = 0.f;
#pragma unroll
    for (int j = 0; j < 4; ++j) {
        float4 a = de4[j * 64 + lane];
        float4 wv = wc4[j * 64 + lane];
        s += a.x * wv.x + a.y * wv.y + a.z * wv.z + a.w * wv.w;
    }
#pragma unroll
    for (int j = 0; j < 4; ++j) {
        float4 a = ap4[j * 64 + lane];
        float4 wv = wc4[256 + j * 64 + lane];
        s += a.x * wv.x + a.y * wv.y + a.z * wv.z + a.w * wv.w;
    }
#pragma unroll
    for (int m = 32; m; m >>= 1) s += __shfl_xor(s, m);
    if (lane == 0) out0[b * DD + d] = tanh_fast(s + bc[d]);
}

// ---------------------------------------------------------------------------
extern "C" void kernel_launch(void* const* d_in, const int* in_sizes, int n_in,
                              void* d_out, int out_size, void* d_ws, size_t ws_size,
                              hipStream_t stream) {
    const float* hidden = (const float*)d_in[0]; // [64,1024]
    const float* dec    = (const float*)d_in[1]; // [64,1024]
    const float* enc    = (const float*)d_in[2]; // [512,64,1024]
    const float* Wa     = (const float*)d_in[3]; // [2048,2048]
    const float* ba     = (const float*)d_in[4]; // [2048]
    const float* w2     = (const float*)d_in[5]; // [2048]
    // d_in[6] = b2: uniform shift of scores -> softmax-invariant, unused.
    const float* Wc     = (const float*)d_in[7]; // [1024,2048]
    const float* bc     = (const float*)d_in[8]; // [1024]
    float* out = (float*)d_out;                  // [64*1024 out | 64*1024 applied]

    unsigned short* encS = (unsigned short*)d_ws;               // 33554432 bf16 (tiled)
    unsigned short* WaS  = encS + (size_t)33554432;             //  2097152 bf16 (tiled)
    float* hp      = (float*)(WaS + (size_t)2097152);           //   131072 f32
    float* scoresP = hp + 131072;                               //   262144 f32 (8 partials)
    float* weights = scoresP + 262144;                          //    32768 f32
    float* part    = weights + 32768;                           //  1048576 f32

    dim3 gc(256, 16);
    conv_encS_kernel<<<gc, 256, 0, stream>>>(enc, encS);
    dim3 gw(16, 16);
    conv_waS_kernel<<<gw, 256, 0, stream>>>(Wa, WaS);
    hproj_kernel<<<256, 256, 0, stream>>>(hidden, Wa, ba, hp);
    dim3 g2(8, 256);   // bn fastest: B-tile pinned per XCD, A-tile L3-shared
    gemm_scores<<<g2, 256, 0, stream>>>(encS, WaS, hp, w2, scoresP);
    softmax_kernel<<<BB, 256, 0, stream>>>(scoresP, weights);
    dim3 g3(16, 64);
    applied_part_kernel<<<g3, 256, 0, stream>>>(enc, weights, part);
    applied_reduce_kernel<<<256, 256, 0, stream>>>(part, out + BB * DD);
    combine_kernel<<<16384, 256, 0, stream>>>(dec, out + BB * DD, Wc, bc, out);
}

// Round 7
// 570.066 us; speedup vs baseline: 1.0570x; 1.0570x over previous
//
#include <hip/hip_runtime.h>
#include <hip/hip_bf16.h>

// B=64 batch, T=512 enc timesteps, E=1024 enc hidden, D=1024 dec hidden
// ALL inputs/outputs are FLOAT32 (per reference setup_inputs).
#define BB 64
#define TT 512
#define EE 1024
#define DD 1024
// Fused e-proj GEMM: M = T*B = 32768, N = 2E = 2048, K = E = 1024 (bf16 MFMA)

typedef __attribute__((ext_vector_type(8))) short s16x8;   // 8 bf16 MFMA A/B frag
typedef __attribute__((ext_vector_type(4))) float f32x4;   // MFMA C/D frag

__device__ __forceinline__ float bf2f(unsigned short u) {
    unsigned int x = ((unsigned int)u) << 16;
    return __builtin_bit_cast(float, x);
}
__device__ __forceinline__ unsigned short f2bf(float f) {   // RNE, finite inputs
    unsigned int u = __builtin_bit_cast(unsigned int, f);
    u += 0x7FFF + ((u >> 16) & 1);
    return (unsigned short)(u >> 16);
}
__device__ __forceinline__ float tanh_fast(float x) {
    x = fminf(fmaxf(x, -15.f), 15.f);
    float e = __expf(2.f * x);
    return (e - 1.f) / (e + 1.f);
}

// Fragment-order slot for chunk (row 0..127, g 0..7) in a 128x64 tile:
//   slot = (row>>4)*128 + (g>>2)*64 + (g&3)*16 + (row&15)
// Fragment (m16, kk) = slots m16*128 + kk*64 + [lane 0..63]  -> lane holds
// A[row=m16*16+(lane&15)][k=kk*32+(lane>>4)*8 .. +8]  (16x16x32 A/B layout).
__device__ __forceinline__ int tile_slot(int row, int g) {
    return (row >> 4) * 128 + (g >> 2) * 64 + (g & 3) * 16 + (row & 15);
}

// ---------------------------------------------------------------------------
// PREP (fused): blocks [0,4096) conv enc->encS tiles; [4096,4352) conv
// Wa right half -> WaS tiles; [4352,4608) hproj; [4608,4624) zero applied.
// All independent; fusing removes 3 serialized launches.
// ---------------------------------------------------------------------------
__global__ __launch_bounds__(256) void prep_kernel(
    const float* __restrict__ enc,       // [32768,1024]
    const float* __restrict__ Wa,        // [2048,2048]
    const float* __restrict__ hidden,    // [64,1024]
    const float* __restrict__ ba,        // [2048]
    unsigned short* __restrict__ encS,   // tiled bf16
    unsigned short* __restrict__ WaS,    // tiled bf16
    float* __restrict__ hp,              // [2048*64] f-major
    float* __restrict__ out_applied)     // [64*1024] zero-init target
{
    const int blk = blockIdx.x;
    const int tid = threadIdx.x;

    if (blk < 4096) {
        // ---- conv enc -> encS tile (tm, tk) ----
        const int tm = blk >> 4;
        const int tk = blk & 15;
        unsigned short* dst = encS + ((size_t)tm * 16 + tk) * 8192;
#pragma unroll
        for (int it = 0; it < 4; ++it) {
            int cidx = it * 256 + tid;       // chunk id 0..1023
            int row  = cidx >> 3;
            int g    = cidx & 7;
            const float* src = enc + (size_t)(tm * 128 + row) * 1024 + tk * 64 + g * 8;
            float4 v0 = ((const float4*)src)[0];
            float4 v1 = ((const float4*)src)[1];
            short c[8];
            c[0] = (short)f2bf(v0.x); c[1] = (short)f2bf(v0.y);
            c[2] = (short)f2bf(v0.z); c[3] = (short)f2bf(v0.w);
            c[4] = (short)f2bf(v1.x); c[5] = (short)f2bf(v1.y);
            c[6] = (short)f2bf(v1.z); c[7] = (short)f2bf(v1.w);
            *(s16x8*)&dst[tile_slot(row, g) * 8] = *(s16x8*)c;
        }
    } else if (blk < 4352) {
        // ---- conv Wa[:,1024:] -> WaS tile (tn, tk) ----
        const int t  = blk - 4096;
        const int tn = t >> 4;
        const int tk = t & 15;
        unsigned short* dst = WaS + ((size_t)tn * 16 + tk) * 8192;
#pragma unroll
        for (int it = 0; it < 4; ++it) {
            int cidx = it * 256 + tid;
            int row  = cidx >> 3;
            int g    = cidx & 7;
            const float* src = Wa + (size_t)(tn * 128 + row) * 2048 + 1024 + tk * 64 + g * 8;
            float4 v0 = ((const float4*)src)[0];
            float4 v1 = ((const float4*)src)[1];
            short c[8];
            c[0] = (short)f2bf(v0.x); c[1] = (short)f2bf(v0.y);
            c[2] = (short)f2bf(v0.z); c[3] = (short)f2bf(v0.w);
            c[4] = (short)f2bf(v1.x); c[5] = (short)f2bf(v1.y);
            c[6] = (short)f2bf(v1.z); c[7] = (short)f2bf(v1.w);
            *(s16x8*)&dst[tile_slot(row, g) * 8] = *(s16x8*)c;
        }
    } else if (blk < 4608) {
        // ---- hproj: 8 f-rows per block ----
        __shared__ float sW[8 * 1024];      // 32 KB
        const int lane = tid & 63;
        const int wave = tid >> 6;
        const int f0   = (blk - 4352) * 8;
#pragma unroll
        for (int i = 0; i < 8; ++i) {
            int idx = i * 256 + tid;
            int fi  = idx >> 8;
            int c4  = idx & 255;
            ((float4*)sW)[idx] = *(const float4*)(Wa + (size_t)(f0 + fi) * 2048 + c4 * 4);
        }
        __syncthreads();
        for (int bi = 0; bi < 16; ++bi) {
            int b = wave * 16 + bi;
            float h[16];
#pragma unroll
            for (int j = 0; j < 16; ++j) h[j] = hidden[b * 1024 + lane + 64 * j];
#pragma unroll
            for (int fi = 0; fi < 8; ++fi) {
                float s = 0.f;
#pragma unroll
                for (int j = 0; j < 16; ++j) s += h[j] * sW[fi * 1024 + lane + 64 * j];
#pragma unroll
                for (int m = 32; m; m >>= 1) s += __shfl_xor(s, m);
                if (lane == 0) hp[(f0 + fi) * 64 + b] = s + ba[f0 + fi];
            }
        }
    } else {
        // ---- zero the applied output region (atomicAdd target) ----
        int idx = (blk - 4608) * 256 + tid;   // 4096 threads x 16 floats
        float4 z = {0.f, 0.f, 0.f, 0.f};
#pragma unroll
        for (int j = 0; j < 4; ++j)
            ((float4*)out_applied)[idx * 4 + j] = z;
    }
}

// ---------------------------------------------------------------------------
// Fused e_proj GEMM + tanh + w2-dot -> per-bn partial scores.  (R5 config.)
// Direct global->VGPR fragments from pre-swizzled tiles, register dbuf,
// barrier-free K-loop. Wave tile 64x128 (4 mi x 8 ni), block = 128x256.
// grid = (256 bm, 8 bn), bm fastest (XCD = bm%8: WaS broadcast-cached,
// encS bm-slices partitioned across XCDs — best measured config, R5).
// ---------------------------------------------------------------------------
__global__ __launch_bounds__(256, 2) void gemm_scores(
    const unsigned short* __restrict__ encS,  // tiled bf16 (ws)
    const unsigned short* __restrict__ WaS,   // tiled bf16 (ws)
    const float* __restrict__ hp,             // [2048*64] f32, f-major
    const float* __restrict__ w2,             // [2048] f32
    float* __restrict__ scoresP)              // [8][64][512] partials
{
    __shared__ float rowAcc[128];

    const int tid  = threadIdx.x;
    const int bm   = blockIdx.x;   // 0..255 row tile (128 rows)
    const int bn   = blockIdx.y;   // 0..7   col tile (256 f)
    const int lane = tid & 63;
    const int wave = tid >> 6;
    const int wm   = wave >> 1;    // 0..1: rows wm*64
    const int wn   = wave & 1;     // 0..1: f-tile tn = bn*2+wn
    const int c    = lane & 15;
    const int quad = lane >> 4;

    if (tid < 128) rowAcc[tid] = 0.f;

    f32x4 acc[4][8];
#pragma unroll
    for (int mi = 0; mi < 4; ++mi)
#pragma unroll
        for (int ni = 0; ni < 8; ++ni)
#pragma unroll
            for (int r = 0; r < 4; ++r) acc[mi][ni][r] = 0.f;

    const unsigned short* aBase = encS + (size_t)bm * 16 * 8192 + wm * 4096 + lane * 8;
    const unsigned short* bBase = WaS + ((size_t)(bn * 2 + wn) * 16) * 8192 + lane * 8;

    s16x8 aF[2][4], bF[2][8];

#pragma unroll
    for (int mi = 0; mi < 4; ++mi)
        aF[0][mi] = *(const s16x8*)(aBase + mi * 1024);
#pragma unroll
    for (int ni = 0; ni < 8; ++ni)
        bF[0][ni] = *(const s16x8*)(bBase + ni * 1024);

#pragma unroll
    for (int h = 0; h < 32; ++h) {
        const int cur = h & 1;
        const int nxt = cur ^ 1;
        if (h < 31) {
            const int h1 = h + 1;
            const unsigned short* pa = aBase + (h1 >> 1) * 8192 + (h1 & 1) * 512;
            const unsigned short* pb = bBase + (h1 >> 1) * 8192 + (h1 & 1) * 512;
#pragma unroll
            for (int mi = 0; mi < 4; ++mi)
                aF[nxt][mi] = *(const s16x8*)(pa + mi * 1024);
#pragma unroll
            for (int ni = 0; ni < 8; ++ni)
                bF[nxt][ni] = *(const s16x8*)(pb + ni * 1024);
        }
#pragma unroll
        for (int mi = 0; mi < 4; ++mi)
#pragma unroll
            for (int ni = 0; ni < 8; ++ni)
                acc[mi][ni] = __builtin_amdgcn_mfma_f32_16x16x32_bf16(
                    aF[cur][mi], bF[cur][ni], acc[mi][ni], 0, 0, 0);
    }

    __syncthreads();   // rowAcc init visible

    float w2v[8];
#pragma unroll
    for (int ni = 0; ni < 8; ++ni)
        w2v[ni] = w2[bn * 256 + wn * 128 + ni * 16 + c];

#pragma unroll
    for (int mi = 0; mi < 4; ++mi) {
        int lrow0 = wm * 64 + mi * 16 + quad * 4;       // quad*4-aligned
        int b0    = (bm * 128 + lrow0) & 63;            // float4-aligned
        f32x4 hp4[8];
#pragma unroll
        for (int ni = 0; ni < 8; ++ni)
            hp4[ni] = *(const f32x4*)&hp[(bn * 256 + wn * 128 + ni * 16 + c) * 64 + b0];
#pragma unroll
        for (int r = 0; r < 4; ++r) {
            float s = 0.f;
#pragma unroll
            for (int ni = 0; ni < 8; ++ni)
                s += tanh_fast(acc[mi][ni][r] + hp4[ni][r]) * w2v[ni];
            s += __shfl_xor(s, 1);
            s += __shfl_xor(s, 2);
            s += __shfl_xor(s, 4);
            s += __shfl_xor(s, 8);
            if (c == 0) atomicAdd(&rowAcc[lrow0 + r], s);
        }
    }
    __syncthreads();
    if (tid < 128) {
        int grow = bm * 128 + tid;
        int b = grow & 63;
        int t = grow >> 6;
        scoresP[((size_t)bn * 64 + b) * 512 + t] = rowAcc[tid];
    }
}

// ---------------------------------------------------------------------------
// APPLIED (softmax fused): grid (8 tc, 64 b), block 256.
// Each block: (1) sums the 8 bn-partials of scores row b, block-softmax
// (redundant per tc — 16 KB read, cheap); (2) weighted sum of enc rows for
// its 64 t's; (3) atomicAdd into out_applied (zeroed by prep).
// ---------------------------------------------------------------------------
__global__ __launch_bounds__(256) void applied_kernel(
    const float* __restrict__ enc,            // [T,B,E] f32
    const float* __restrict__ scoresP,        // [8][64][512]
    float* __restrict__ out_applied)          // [64][1024] (output 2)
{
    __shared__ float red[4];
    __shared__ float wts[64];
    const int tc  = blockIdx.x;        // t-chunk: t = tc*64 .. +63
    const int b   = blockIdx.y;
    const int tid = threadIdx.x;

    // --- softmax over the full 512 row (each thread owns cols tid, tid+256)
    float v0 = 0.f, v1 = 0.f;
#pragma unroll
    for (int p = 0; p < 8; ++p) {
        const float* row = scoresP + ((size_t)p * 64 + b) * 512;
        v0 += row[tid];
        v1 += row[tid + 256];
    }
    float m = fmaxf(v0, v1);
#pragma unroll
    for (int s = 32; s; s >>= 1) m = fmaxf(m, __shfl_xor(m, s));
    if ((tid & 63) == 0) red[tid >> 6] = m;
    __syncthreads();
    m = fmaxf(fmaxf(red[0], red[1]), fmaxf(red[2], red[3]));
    __syncthreads();
    float e0 = __expf(v0 - m), e1 = __expf(v1 - m);
    float s = e0 + e1;
#pragma unroll
    for (int t = 32; t; t >>= 1) s += __shfl_xor(s, t);
    if ((tid & 63) == 0) red[tid >> 6] = s;
    __syncthreads();
    float inv = 1.f / (red[0] + red[1] + red[2] + red[3]);
    // stash this block's 64 weights (cols tc*64..+63 live in threads)
    if ((tid & 255) >= (tc * 64 & 255)) {}   // no-op; clarity
    if (tid >= tc * 64 && tid < tc * 64 + 64 && tc < 4)
        wts[tid - tc * 64] = e0 * inv;
    if (tid + 256 >= tc * 64 && tid + 256 < tc * 64 + 64 && tc >= 4)
        wts[tid + 256 - tc * 64] = e1 * inv;
    __syncthreads();

    // --- weighted sum over 64 t's; 128 e-owners x 2 t-halves
    const int eo = tid & 127;
    const int th = tid >> 7;
    const int e0i = eo * 8;
    float a[8];
#pragma unroll
    for (int j = 0; j < 8; ++j) a[j] = 0.f;
    for (int it = 0; it < 32; ++it) {
        int tl = th * 32 + it;                 // 0..63 local t
        int t  = tc * 64 + tl;
        float wt = wts[tl];
        const float* src = enc + ((size_t)(t * BB + b)) * EE + e0i;
        float4 u0 = ((const float4*)src)[0];
        float4 u1 = ((const float4*)src)[1];
        a[0] += wt * u0.x; a[1] += wt * u0.y; a[2] += wt * u0.z; a[3] += wt * u0.w;
        a[4] += wt * u1.x; a[5] += wt * u1.y; a[6] += wt * u1.z; a[7] += wt * u1.w;
    }
    float* dst = out_applied + (size_t)b * 1024 + e0i;
#pragma unroll
    for (int j = 0; j < 8; ++j) atomicAdd(&dst[j], a[j]);
}

// ---------------------------------------------------------------------------
// out[b,d] = tanh(dec[b].Wc[d,:1024] + applied[b].Wc[d,1024:] + bc[d])
// ---------------------------------------------------------------------------
__global__ __launch_bounds__(256) void combine_kernel(
    const float* __restrict__ dec,       // [64,1024]
    const float* applied,                // [64,1024] (= out+65536)
    const float* __restrict__ Wc,        // [1024,2048]
    const float* __restrict__ bc,        // [1024]
    float* out0)                         // first 65536 of d_out
{
    const int g    = blockIdx.x * 4 + (threadIdx.x >> 6);
    const int lane = threadIdx.x & 63;
    const int d    = g >> 6;
    const int b    = g & 63;

    const float4* wc4 = (const float4*)Wc + (size_t)d * 512;
    const float4* de4 = (const float4*)dec + (size_t)b * 256;
    const float4* ap4 = (const float4*)applied + (size_t)b * 256;

    float s = 0.f;
#pragma unroll
    for (int j = 0; j < 4; ++j) {
        float4 a = de4[j * 64 + lane];
        float4 wv = wc4[j * 64 + lane];
        s += a.x * wv.x + a.y * wv.y + a.z * wv.z + a.w * wv.w;
    }
#pragma unroll
    for (int j = 0; j < 4; ++j) {
        float4 a = ap4[j * 64 + lane];
        float4 wv = wc4[256 + j * 64 + lane];
        s += a.x * wv.x + a.y * wv.y + a.z * wv.z + a.w * wv.w;
    }
#pragma unroll
    for (int m = 32; m; m >>= 1) s += __shfl_xor(s, m);
    if (lane == 0) out0[b * DD + d] = tanh_fast(s + bc[d]);
}

// ---------------------------------------------------------------------------
extern "C" void kernel_launch(void* const* d_in, const int* in_sizes, int n_in,
                              void* d_out, int out_size, void* d_ws, size_t ws_size,
                              hipStream_t stream) {
    const float* hidden = (const float*)d_in[0]; // [64,1024]
    const float* dec    = (const float*)d_in[1]; // [64,1024]
    const float* enc    = (const float*)d_in[2]; // [512,64,1024]
    const float* Wa     = (const float*)d_in[3]; // [2048,2048]
    const float* ba     = (const float*)d_in[4]; // [2048]
    const float* w2     = (const float*)d_in[5]; // [2048]
    // d_in[6] = b2: uniform shift of scores -> softmax-invariant, unused.
    const float* Wc     = (const float*)d_in[7]; // [1024,2048]
    const float* bc     = (const float*)d_in[8]; // [1024]
    float* out = (float*)d_out;                  // [64*1024 out | 64*1024 applied]

    unsigned short* encS = (unsigned short*)d_ws;               // 33554432 bf16 (tiled)
    unsigned short* WaS  = encS + (size_t)33554432;             //  2097152 bf16 (tiled)
    float* hp      = (float*)(WaS + (size_t)2097152);           //   131072 f32
    float* scoresP = hp + 131072;                               //   262144 f32 (8 partials)

    float* out_applied = out + BB * DD;

    prep_kernel<<<4624, 256, 0, stream>>>(enc, Wa, hidden, ba, encS, WaS, hp, out_applied);
    dim3 g2(256, 8);
    gemm_scores<<<g2, 256, 0, stream>>>(encS, WaS, hp, w2, scoresP);
    dim3 g3(8, 64);
    applied_kernel<<<g3, 256, 0, stream>>>(enc, scoresP, out_applied);
    combine_kernel<<<16384, 256, 0, stream>>>(dec, out_applied, Wc, bc, out);
}